// Round 7
// baseline (351.755 us; speedup 1.0000x reference)
//
#include <hip/hip_runtime.h>
#include <hip/hip_bf16.h>

// B=16, S=1024, D=1024, H=16, HD=64.
// energy = -sum_{b,h,s} logsumexp_t( beta_h * q.k, t != s ) / beta_h
// Q pre-scaled by beta_h*log2e at projection; attn inner loop = v_exp_f32 only.

using short8  = __attribute__((ext_vector_type(8))) short;
using f32x4   = __attribute__((ext_vector_type(4))) float;
using ushort8 = __attribute__((ext_vector_type(8))) unsigned short;
using float4v = __attribute__((ext_vector_type(4))) float;

#define B_  16
#define S_  1024
#define D_  1024
#define H_  16
#define HD_ 64
#define LOG2E 1.4426950408889634f
#define LN2   0.6931471805599453f

#if __has_builtin(__builtin_amdgcn_exp2f)
#define EXP2F(x) __builtin_amdgcn_exp2f(x)
#else
#define EXP2F(x) exp2f(x)
#endif
#if __has_builtin(__builtin_amdgcn_logf)
#define LOG2F(x) __builtin_amdgcn_logf(x)
#else
#define LOG2F(x) log2f(x)
#endif

__device__ inline unsigned short f2bf(float f) {
  union { float f; unsigned u; } v; v.f = f;
  unsigned r = v.u + 0x7FFFu + ((v.u >> 16) & 1u);   // RNE
  return (unsigned short)(r >> 16);
}

// ---------------- fp32 -> bf16 convert ----------------
__global__ __launch_bounds__(256) void cvt_bf16_k(const float* __restrict__ in,
                                                  unsigned short* __restrict__ out, int n8) {
  int i = blockIdx.x * 256 + threadIdx.x;
  if (i >= n8) return;
  const float4v* p = (const float4v*)in;
  float4v a = p[2 * i], b = p[2 * i + 1];
  ushort8 r;
  r[0] = f2bf(a[0]); r[1] = f2bf(a[1]); r[2] = f2bf(a[2]); r[3] = f2bf(a[3]);
  r[4] = f2bf(b[0]); r[5] = f2bf(b[1]); r[6] = f2bf(b[2]); r[7] = f2bf(b[3]);
  ((ushort8*)out)[i] = r;
}

__global__ void zero_out_k(float* o) { if (threadIdx.x == 0) *o = 0.f; }

// ---------------- staging: global -> LDS, [128 rows][64 bf16] tile ----------------
__device__ inline void gload_lds16(const void* g, void* l) {
  __builtin_amdgcn_global_load_lds((const __attribute__((address_space(1))) void*)g,
                                   (__attribute__((address_space(3))) void*)l, 16, 0, 0);
}

__device__ inline void stage_tile(const char* src, int stride, char* lds, int tid) {
  int lane = tid & 63, wave = tid >> 6;
#pragma unroll
  for (int r = 0; r < 4; ++r) {
    int o   = r * 4096 + wave * 1024 + lane * 16;
    int row = o >> 7;
    int kb  = o & 127;
    int skb = kb ^ ((row & 7) << 4);                // involutive swizzle (rule #21)
    gload_lds16(src + (size_t)row * stride + skb, lds + (r * 4096 + wave * 1024));
  }
}

__device__ inline short8 ld_frag(const char* lds, int row, int kk, int lane) {
  int kb   = kk * 64 + ((lane >> 4) << 4);
  int addr = row * 128 + (kb ^ ((row & 7) << 4));
  return *(const short8*)(lds + addr);
}

// ---------------- merged projection GEMM (Q and K share the A-tile) ----------------
// grid 1024 = 128 m-panels x 8 n-panels, chunked XCD swizzle. Per block:
// stage A, Bq, Bk (48 KB LDS) -> 64 MFMA/wave per K-step (was 32 with 16 reads;
// now 24 reads): staging+ds_read per MFMA -25%.
__global__ __launch_bounds__(256) void proj_gemm_k(const unsigned short* __restrict__ Xb,
                                                   const unsigned short* __restrict__ Wqb,
                                                   const unsigned short* __restrict__ Wkb,
                                                   const float* __restrict__ beta,
                                                   unsigned short* __restrict__ Qg,
                                                   unsigned short* __restrict__ Kg) {
  __shared__ char As[16384];
  __shared__ char Bqs[16384];
  __shared__ char Bks[16384];
  const int tid = threadIdx.x, lane = tid & 63, wave = tid >> 6;
  const int wr = wave >> 1, wc = wave & 1;
  const int wgid = (blockIdx.x & 7) * 128 + (blockIdx.x >> 3);  // 1024 % 8 == 0
  const int mt = wgid >> 3, np = wgid & 7;
  const int m0 = mt * 128, n0 = np * 128;
  const char* Abase  = (const char*)Xb  + (size_t)m0 * (D_ * 2);
  const char* Bqbase = (const char*)Wqb + (size_t)n0 * (D_ * 2);
  const char* Bkbase = (const char*)Wkb + (size_t)n0 * (D_ * 2);

  f32x4 accq[4][4], acck[4][4];
#pragma unroll
  for (int i = 0; i < 4; ++i)
#pragma unroll
    for (int j = 0; j < 4; ++j)
#pragma unroll
      for (int q = 0; q < 4; ++q) { accq[i][j][q] = 0.f; acck[i][j][q] = 0.f; }

  for (int kt = 0; kt < D_ / 64; ++kt) {
    stage_tile(Abase  + kt * 128, D_ * 2, As,  tid);
    stage_tile(Bqbase + kt * 128, D_ * 2, Bqs, tid);
    stage_tile(Bkbase + kt * 128, D_ * 2, Bks, tid);
    __syncthreads();
#pragma unroll
    for (int kk = 0; kk < 2; ++kk) {
      short8 a[4];
#pragma unroll
      for (int i = 0; i < 4; ++i) a[i] = ld_frag(As, wr * 64 + i * 16 + (lane & 15), kk, lane);
#pragma unroll
      for (int j = 0; j < 4; ++j) {
        short8 bq = ld_frag(Bqs, wc * 64 + j * 16 + (lane & 15), kk, lane);
#pragma unroll
        for (int i = 0; i < 4; ++i)
          accq[i][j] = __builtin_amdgcn_mfma_f32_16x16x32_bf16(a[i], bq, accq[i][j], 0, 0, 0);
        short8 bk = ld_frag(Bks, wc * 64 + j * 16 + (lane & 15), kk, lane);
#pragma unroll
        for (int i = 0; i < 4; ++i)
          acck[i][j] = __builtin_amdgcn_mfma_f32_16x16x32_bf16(a[i], bk, acck[i][j], 0, 0, 0);
      }
    }
    __syncthreads();
  }

  // head uniform per wave: n = n0 + wc*64 + [0,64) -> h = np*2 + wc
  const float scl = beta[np * 2 + wc] * LOG2E;
#pragma unroll
  for (int mi = 0; mi < 4; ++mi)
#pragma unroll
    for (int ni = 0; ni < 4; ++ni)
#pragma unroll
      for (int j = 0; j < 4; ++j) {
        int m = m0 + wr * 64 + mi * 16 + ((lane >> 4) << 2) + j;
        int n = n0 + wc * 64 + ni * 16 + (lane & 15);
        int bb = m >> 10, s = m & (S_ - 1);
        int h = n >> 6, hd = n & (HD_ - 1);
        size_t o = (((size_t)bb * H_ + h) * S_ + s) * HD_ + hd;
        Qg[o] = f2bf(accq[mi][ni][j] * scl);
        Kg[o] = f2bf(acck[mi][ni][j]);
      }
}

// ---------------- fused scores + masked LSE + energy: ZERO LDS / ZERO barriers ----------------
// K panel per (b,h) = 128 KB, L2-resident (8 q-tile blocks share it on one XCD
// via chunked swizzle) -> load Q,K fragments straight global->VGPR (mistake #7:
// don't LDS-stage L2-fit data). 2-deep pipelined 64-key chunks; waves independent.
__device__ inline void attn_loadk(short8 (&kf)[2][4], const char* kbase, int tb, int lane) {
#pragma unroll
  for (int kk = 0; kk < 2; ++kk)
#pragma unroll
    for (int nj = 0; nj < 4; ++nj)
      kf[kk][nj] = *(const short8*)(kbase +
          (size_t)((tb * 64 + nj * 16 + (lane & 15)) * 128 + kk * 64 + ((lane >> 4) << 4)));
}

__device__ inline void attn_step(const short8 (&qa)[2][2], const short8 (&kf)[2][4],
                                 float (&rs)[2][4], int tb, int dgtb, int q0w, int lane) {
  f32x4 acc[2][4];
#pragma unroll
  for (int mi = 0; mi < 2; ++mi)
#pragma unroll
    for (int nj = 0; nj < 4; ++nj)
#pragma unroll
      for (int q = 0; q < 4; ++q) acc[mi][nj][q] = 0.f;
#pragma unroll
  for (int kk = 0; kk < 2; ++kk)
#pragma unroll
    for (int nj = 0; nj < 4; ++nj) {
      acc[0][nj] = __builtin_amdgcn_mfma_f32_16x16x32_bf16(qa[0][kk], kf[kk][nj], acc[0][nj], 0, 0, 0);
      acc[1][nj] = __builtin_amdgcn_mfma_f32_16x16x32_bf16(qa[1][kk], kf[kk][nj], acc[1][nj], 0, 0, 0);
    }
  if (tb == dgtb) {   // wave-uniform branch; 1 of 16 chunks
#pragma unroll
    for (int mi = 0; mi < 2; ++mi)
#pragma unroll
      for (int nj = 0; nj < 4; ++nj) {
        f32x4 v = acc[mi][nj];
#pragma unroll
        for (int j = 0; j < 4; ++j) {
          int q = q0w + mi * 16 + ((lane >> 4) << 2) + j;
          int t = tb * 64 + nj * 16 + (lane & 15);
          rs[mi][j] += EXP2F(q == t ? -1e30f : v[j]);   // diagonal -> exp2 = 0
        }
      }
  } else {
#pragma unroll
    for (int mi = 0; mi < 2; ++mi)
#pragma unroll
      for (int nj = 0; nj < 4; ++nj) {
        f32x4 v = acc[mi][nj];
#pragma unroll
        for (int j = 0; j < 4; ++j) rs[mi][j] += EXP2F(v[j]);
      }
  }
}

__global__ __launch_bounds__(256) void attn_lse_k(const unsigned short* __restrict__ Qg,
                                                  const unsigned short* __restrict__ Kg,
                                                  const float* __restrict__ beta,
                                                  float* __restrict__ out) {
  __shared__ float wsum[4];
  const int tid = threadIdx.x, lane = tid & 63, wave = tid >> 6;
  const int wgid = (blockIdx.x & 7) * 256 + (blockIdx.x >> 3);
  const int qt = wgid & 7, hb = wgid >> 3;
  const int h = hb & 15, b = hb >> 4;
  const char* qbase = (const char*)Qg + (((size_t)b * H_ + h) * S_) * (HD_ * 2);
  const char* kbase = (const char*)Kg + (((size_t)b * H_ + h) * S_) * (HD_ * 2);
  const int q0w = qt * 128 + wave * 32;
  const int dgtb = q0w >> 6;   // 64-key chunk containing this wave's diagonal

  short8 qa[2][2];   // loop-invariant Q fragments, straight from global
#pragma unroll
  for (int mi = 0; mi < 2; ++mi)
#pragma unroll
    for (int kk = 0; kk < 2; ++kk)
      qa[mi][kk] = *(const short8*)(qbase +
          (size_t)((q0w + mi * 16 + (lane & 15)) * 128 + kk * 64 + ((lane >> 4) << 4)));

  float rs[2][4];
#pragma unroll
  for (int mi = 0; mi < 2; ++mi)
#pragma unroll
    for (int j = 0; j < 4; ++j) rs[mi][j] = 0.f;

  short8 kfA[2][4], kfB[2][4];
  attn_loadk(kfA, kbase, 0, lane);
#pragma unroll
  for (int tb = 0; tb < 16; ++tb) {
    if ((tb & 1) == 0) {
      if (tb < 15) attn_loadk(kfB, kbase, tb + 1, lane);
      attn_step(qa, kfA, rs, tb, dgtb, q0w, lane);
    } else {
      if (tb < 15) attn_loadk(kfA, kbase, tb + 1, lane);
      attn_step(qa, kfB, rs, tb, dgtb, q0w, lane);
    }
  }

  // row-sum across the 16 lanes of each 16-lane group, then log2
  float local = 0.f;
#pragma unroll
  for (int mi = 0; mi < 2; ++mi)
#pragma unroll
    for (int j = 0; j < 4; ++j) {
      float v = rs[mi][j];
      v += __shfl_xor(v, 1); v += __shfl_xor(v, 2);
      v += __shfl_xor(v, 4); v += __shfl_xor(v, 8);
      local += LOG2F(v);
    }
  local += __shfl_xor(local, 16);
  local += __shfl_xor(local, 32);
  if (lane == 0) wsum[wave] = local;
  __syncthreads();
  if (tid == 0) {
    float t = wsum[0] + wsum[1] + wsum[2] + wsum[3];
    atomicAdd(out, -t * LN2 / beta[h]);
  }
}

// ---------------- launcher ----------------
extern "C" void kernel_launch(void* const* d_in, const int* in_sizes, int n_in,
                              void* d_out, int out_size, void* d_ws, size_t ws_size,
                              hipStream_t stream) {
  const float* x    = (const float*)d_in[0];
  const float* qw   = (const float*)d_in[1];
  const float* kw   = (const float*)d_in[2];
  const float* beta = (const float*)d_in[3];
  float* out = (float*)d_out;

  char* ws = (char*)d_ws;
  unsigned short* Xb  = (unsigned short*)(ws);              // 33554432 B
  unsigned short* Wqb = (unsigned short*)(ws + 33554432);   //  2097152 B
  unsigned short* Wkb = (unsigned short*)(ws + 35651584);   //  2097152 B
  unsigned short* Qg  = (unsigned short*)(ws + 37748736);   // 33554432 B
  unsigned short* Kg  = (unsigned short*)(ws + 71303168);   // 33554432 B (end 104857600)

  cvt_bf16_k<<<8192, 256, 0, stream>>>(x,  Xb,  (B_ * S_ * D_) / 8);
  cvt_bf16_k<<<512,  256, 0, stream>>>(qw, Wqb, (H_ * HD_ * D_) / 8);
  cvt_bf16_k<<<512,  256, 0, stream>>>(kw, Wkb, (H_ * HD_ * D_) / 8);
  zero_out_k<<<1, 64, 0, stream>>>(out);
  proj_gemm_k<<<1024, 256, 0, stream>>>(Xb, Wqb, Wkb, beta, Qg, Kg);
  attn_lse_k<<<2048, 256, 0, stream>>>(Qg, Kg, beta, out);
}